// Round 6
// baseline (256.738 us; speedup 1.0000x reference)
//
#include <hip/hip_runtime.h>
#include <math.h>

typedef __bf16 bf16x8 __attribute__((ext_vector_type(8)));
typedef float f32x4 __attribute__((ext_vector_type(4)));
typedef unsigned short u16x8 __attribute__((ext_vector_type(8)));
typedef unsigned short u16x4v __attribute__((ext_vector_type(4)));

__device__ __forceinline__ unsigned short f2bf(float f){
  unsigned u = __builtin_bit_cast(unsigned, f);
  u += 0x7fffu + ((u>>16)&1u);
  return (unsigned short)(u>>16);
}
__device__ __forceinline__ unsigned pack2(float a, float b){
  return (unsigned)f2bf(a) | ((unsigned)f2bf(b)<<16);
}
__device__ __forceinline__ float bf2f(unsigned short h){
  unsigned u = ((unsigned)h)<<16;
  return __builtin_bit_cast(float, u);
}
__device__ __forceinline__ bf16x8 ldfrag_g(const unsigned short* p){
  u16x8 v = *reinterpret_cast<const u16x8*>(p);
  return __builtin_bit_cast(bf16x8, v);
}
__device__ __forceinline__ f32x4 mfma16(bf16x8 a, bf16x8 b, f32x4 c){
  return __builtin_amdgcn_mfma_f32_16x16x32_bf16(a, b, c, 0, 0, 0);
}

// h-channel permutation: channel c lives at slot c' = (c&15)*16 + (c>>4).
// orig(c') = ((c'&15)<<4) | (c'>>4).

// ============ k0: weights fp32 -> bf16 MFMA fragment layout (+ tap repack) ============
__global__ __launch_bounds__(64) void k0_wfrag(
  const float* __restrict__ Wk, const float* __restrict__ Wq,
  const float* __restrict__ Wv, const float* __restrict__ Wr,
  const float* __restrict__ W1, const float* __restrict__ W2,
  const float* __restrict__ dww, const float* __restrict__ dwb,
  float* __restrict__ dwp, unsigned short* __restrict__ wf)
{
  const int bid = blockIdx.x, l = threadIdx.x;
  if (bid == 96){
    // taps+bias keyed by permuted slot c': dwp[c'*12 + j] (j=0..8 taps, 9=bias)
    #pragma unroll
    for (int c=0;c<4;++c){
      int cp = l*4 + c;
      int f = ((cp&15)<<4) | (cp>>4);
      #pragma unroll
      for (int j=0;j<9;++j) dwp[cp*12 + j] = dww[f*9+j];
      dwp[cp*12 + 9]  = dwb[f];
      dwp[cp*12 + 10] = 0.f;
      dwp[cp*12 + 11] = 0.f;
    }
    return;
  }
  const float* src; int K, nt, ks; unsigned short* dst; bool perm = false;
  if (bid < 32){
    int w = bid>>3, f = bid&7;
    src = (w==0)?Wk:(w==1)?Wq:(w==2)?Wv:Wr;
    K = 64; nt = f>>1; ks = f&1;
    dst = wf + w*4096 + f*512;
  } else if (bid < 64){
    int f = bid-32; src = W1; K = 64; nt = f>>1; ks = f&1;
    dst = wf + 16384 + f*512;
  } else {
    int f = bid-64; src = W2; K = 256; nt = f>>3; ks = f&7;
    dst = wf + 32768 + f*512; perm = true;   // k index = permuted slot c'
  }
  u16x8 v;
  #pragma unroll
  for (int j=0;j<8;++j){
    int k = ks*32 + (l>>4)*8 + j;
    if (perm) k = ((k&15)<<4) | (k>>4);
    int n = nt*16 + (l&15);
    v[j] = f2bf(src[n*K + k]);
  }
  *reinterpret_cast<u16x8*>(dst + l*8) = v;
}

// ============ k1: LN1 + K/V proj (MFMA) + ctx accumulation (MFMA, LDS-transpose) ============
__global__ __launch_bounds__(256,2) void k1_ctx(
  const float* __restrict__ x, const float* __restrict__ g1, const float* __restrict__ be1,
  const float* __restrict__ bk, const float* __restrict__ bv,
  const unsigned short* __restrict__ wf,
  float* __restrict__ g_part, float* __restrict__ g_sump)
{
  __shared__ unsigned short tiles[4][4096];
  __shared__ float ctx_l[64*68];
  __shared__ float ssum_l[4][64];
  const int t = threadIdx.x, wid = t>>6, l = t&63;
  const int lg = l>>4, l15 = l&15;
  unsigned short* tile = tiles[wid];
  const int tok0 = blockIdx.x*512 + wid*128;

  bf16x8 WkF[8], WvF[8];
  #pragma unroll
  for (int f=0; f<8; ++f){
    WkF[f] = ldfrag_g(wf +    0 + f*512 + l*8);
    WvF[f] = ldfrag_g(wf + 8192 + f*512 + l*8);
  }
  float4 g1v  = *reinterpret_cast<const float4*>(&g1[l15*4]);
  float4 be1v = *reinterpret_cast<const float4*>(&be1[l15*4]);
  float bkv[4], bvv[4];
  #pragma unroll
  for (int ct=0; ct<4; ++ct){ bkv[ct]=bk[ct*16+l15]; bvv[ct]=bv[ct*16+l15]; }

  f32x4 acc[4][4];
  #pragma unroll
  for (int a=0;a<4;++a)
    #pragma unroll
    for (int b=0;b<4;++b) acc[a][b] = (f32x4){0.f,0.f,0.f,0.f};
  float sume[4] = {0.f,0.f,0.f,0.f};

  for (int tb=0; tb<2; ++tb){
    const int tbase = tok0 + tb*64;
    #pragma unroll
    for (int it=0; it<16; ++it){
      int row = it*4 + lg;
      float4 xv = *reinterpret_cast<const float4*>(&x[(size_t)(tbase+row)*64 + l15*4]);
      float s1 = xv.x+xv.y+xv.z+xv.w;
      float s2 = xv.x*xv.x + xv.y*xv.y + xv.z*xv.z + xv.w*xv.w;
      #pragma unroll
      for (int off=1; off<16; off<<=1){ s1 += __shfl_xor(s1,off,64); s2 += __shfl_xor(s2,off,64); }
      float mu = s1*(1.f/64.f);
      float rs = rsqrtf(s2*(1.f/64.f) - mu*mu + 1e-5f);
      uint2 pk = { pack2((xv.x-mu)*rs*g1v.x + be1v.x, (xv.y-mu)*rs*g1v.y + be1v.y),
                   pack2((xv.z-mu)*rs*g1v.z + be1v.z, (xv.w-mu)*rs*g1v.w + be1v.w) };
      *reinterpret_cast<uint2*>(&tile[row*64 + ((l15*4) ^ ((row&7)<<3))]) = pk;
    }
    bf16x8 aF[4][2];
    #pragma unroll
    for (int mt=0;mt<4;++mt){
      int row = mt*16+l15, sw=(row&7)<<3, ab=row*64;
      aF[mt][0] = __builtin_bit_cast(bf16x8, *reinterpret_cast<const u16x8*>(tile+ab+((     lg*8)^sw)));
      aF[mt][1] = __builtin_bit_cast(bf16x8, *reinterpret_cast<const u16x8*>(tile+ab+((32 + lg*8)^sw)));
    }
    #pragma unroll
    for (int half=0; half<2; ++half){
      #pragma unroll
      for (int m2=0;m2<2;++m2){
        const int mt = half*2+m2;
        #pragma unroll
        for (int ct=0;ct<4;++ct){
          f32x4 z = {0.f,0.f,0.f,0.f};
          z = mfma16(aF[mt][0], WkF[ct*2+0], z);
          z = mfma16(aF[mt][1], WkF[ct*2+1], z);
          float e0=__expf(z[0]+bkv[ct]), e1=__expf(z[1]+bkv[ct]);
          float e2=__expf(z[2]+bkv[ct]), e3=__expf(z[3]+bkv[ct]);
          sume[ct] += (e0+e1)+(e2+e3);
          const int c = ct*16+l15, sw = (c&7)<<3;
          const int cb = m2*16+lg*4;
          uint2 pe = { pack2(e0,e1), pack2(e2,e3) };
          *reinterpret_cast<uint2*>(&tile[c*64 + (cb ^ sw)]) = pe;
          f32x4 w = {0.f,0.f,0.f,0.f};
          w = mfma16(aF[mt][0], WvF[ct*2+0], w);
          w = mfma16(aF[mt][1], WvF[ct*2+1], w);
          uint2 pv = { pack2(w[0]+bvv[ct], w[1]+bvv[ct]), pack2(w[2]+bvv[ct], w[3]+bvv[ct]) };
          *reinterpret_cast<uint2*>(&tile[c*64 + ((32+cb) ^ sw)]) = pv;
        }
      }
      bf16x8 eA[4], vB[4];
      #pragma unroll
      for (int cm=0;cm<4;++cm){
        int row = cm*16+l15, sw=(row&7)<<3;
        eA[cm] = __builtin_bit_cast(bf16x8, *reinterpret_cast<const u16x8*>(tile + row*64 + ((     lg*8)^sw)));
        vB[cm] = __builtin_bit_cast(bf16x8, *reinterpret_cast<const u16x8*>(tile + row*64 + ((32 + lg*8)^sw)));
      }
      #pragma unroll
      for (int cm=0; cm<4; ++cm)
        #pragma unroll
        for (int jn=0; jn<4; ++jn)
          acc[cm][jn] = mfma16(eA[cm], vB[jn], acc[cm][jn]);
    }
  }
  #pragma unroll
  for (int ct=0; ct<4; ++ct){
    float s = sume[ct];
    s += __shfl_xor(s,16,64); s += __shfl_xor(s,32,64);
    if (lg==0) ssum_l[wid][ct*16+l15] = s;
  }
  #define CTX_RED(OP) \
    _Pragma("unroll") for (int cm=0;cm<4;++cm) \
    _Pragma("unroll") for (int jn=0;jn<4;++jn) \
    _Pragma("unroll") for (int r=0;r<4;++r) \
      ctx_l[(cm*16+lg*4+r)*68 + jn*16+l15] OP acc[cm][jn][r];
  if (wid==0){ CTX_RED(=) }  __syncthreads();
  if (wid==1){ CTX_RED(+=) } __syncthreads();
  if (wid==2){ CTX_RED(+=) } __syncthreads();
  if (wid==3){ CTX_RED(+=) } __syncthreads();
  #undef CTX_RED
  for (int i=t; i<4096; i+=256)
    g_part[(size_t)blockIdx.x*4096 + i] = ctx_l[(i>>6)*68 + (i&63)];
  if (t<64)
    g_sump[blockIdx.x*64 + t] = ssum_l[0][t]+ssum_l[1][t]+ssum_l[2][t]+ssum_l[3][t];
}

// ============ k15: reduce partials; ctxWr = (ctx_norm @ Wr^T) -> bf16 frags ============
__global__ __launch_bounds__(512) void k15_ctxwr(
  const float* __restrict__ g_part, const float* __restrict__ g_sump,
  const float* __restrict__ Wr, unsigned short* __restrict__ ctxWrF)
{
  __shared__ float sctx[4096];
  __shared__ float sWr[4096];
  __shared__ float sinv[64];
  const int b = blockIdx.x, t = threadIdx.x;
  if (t<64){
    float s=0.f;
    #pragma unroll 8
    for (int p=0;p<32;++p) s += g_sump[(b*32+p)*64 + t];
    sinv[t] = 1.f/s;
  }
  for (int idx=t; idx<4096; idx+=512){
    float s=0.f;
    #pragma unroll 8
    for (int p=0;p<32;++p) s += g_part[(size_t)(b*32+p)*4096 + idx];
    sctx[idx] = s;
  }
  __syncthreads();
  {
    int c = t>>3, d0 = (t&7)*8;
    float invc = sinv[c];
    #pragma unroll
    for (int dd=0; dd<8; ++dd){
      int d = d0+dd; float s = 0.f;
      #pragma unroll
      for (int v=0; v<64; ++v) s += sctx[c*64+v]*Wr[d*64+v];
      sWr[c*64+d] = s*invc;
    }
  }
  __syncthreads();
  {
    int f = t>>6, l = t&63, nt = f>>1, ks = f&1;
    u16x8 v;
    #pragma unroll
    for (int j=0;j<8;++j){
      int k = ks*32 + (l>>4)*8 + j;
      int n = nt*16 + (l&15);
      v[j] = f2bf(sWr[k*64+n]);
    }
    *reinterpret_cast<u16x8*>(ctxWrF + b*4096 + f*512 + l*8) = v;
  }
}

// ============ k2: LN1 + q-softmax + attn + residual + LN2 -> n2 (bf16, wide stores) ============
__global__ __launch_bounds__(256,2) void k2_attn_ffn1(
  const float* __restrict__ x,
  const float* __restrict__ g1, const float* __restrict__ be1,
  const float* __restrict__ bq, const float* __restrict__ br,
  const float* __restrict__ g2, const float* __restrict__ be2,
  const unsigned short* __restrict__ wf,
  const unsigned short* __restrict__ ctxWrF,
  unsigned short* __restrict__ g_txb, unsigned short* __restrict__ n2g)
{
  __shared__ unsigned short tiles[4][4096];
  const int t = threadIdx.x, wid = t>>6, l = t&63;
  const int l15 = l&15, lg = l>>4;
  unsigned short* tile = tiles[wid];
  const int tok0 = (blockIdx.x*4 + wid)*64;
  const int img  = blockIdx.x>>6;

  bf16x8 WqF[8], CWF[8];
  #pragma unroll
  for (int f=0; f<8; ++f){
    WqF[f] = ldfrag_g(wf + 4096 + f*512 + l*8);
    CWF[f] = ldfrag_g(ctxWrF + img*4096 + f*512 + l*8);
  }
  float4 g1v  = *reinterpret_cast<const float4*>(&g1[l15*4]);
  float4 be1v = *reinterpret_cast<const float4*>(&be1[l15*4]);
  float bqv[4], brv[4], g2v[4], be2v[4];
  #pragma unroll
  for (int nt=0; nt<4; ++nt){
    bqv[nt]=bq[nt*16+l15]; brv[nt]=br[nt*16+l15];
    g2v[nt]=g2[nt*16+l15]; be2v[nt]=be2[nt*16+l15];
  }

  // ---- LN1 -> swizzled bf16 tile ----
  #pragma unroll
  for (int it=0; it<16; ++it){
    int row = it*4 + lg;
    float4 xv = *reinterpret_cast<const float4*>(&x[(size_t)(tok0+row)*64 + l15*4]);
    float s1 = xv.x+xv.y+xv.z+xv.w;
    float s2 = xv.x*xv.x + xv.y*xv.y + xv.z*xv.z + xv.w*xv.w;
    #pragma unroll
    for (int off=1; off<16; off<<=1){ s1 += __shfl_xor(s1,off,64); s2 += __shfl_xor(s2,off,64); }
    float mu = s1*(1.f/64.f);
    float rs = rsqrtf(s2*(1.f/64.f) - mu*mu + 1e-5f);
    uint2 pk = { pack2((xv.x-mu)*rs*g1v.x + be1v.x, (xv.y-mu)*rs*g1v.y + be1v.y),
                 pack2((xv.z-mu)*rs*g1v.z + be1v.z, (xv.w-mu)*rs*g1v.w + be1v.w) };
    *reinterpret_cast<uint2*>(&tile[row*64 + ((l15*4) ^ ((row&7)<<3))]) = pk;
  }

  // ---- phase A: per m-tile attn chain; leaves n2 in the tile ----
  for (int mt=0; mt<4; ++mt){
    const int arow = mt*16 + l15;
    const int asw  = (arow&7)<<3;
    const int abase= arow*64;
    bf16x8 a0 = __builtin_bit_cast(bf16x8, *reinterpret_cast<const u16x8*>(tile + abase + ((     lg*8) ^ asw)));
    bf16x8 a1 = __builtin_bit_cast(bf16x8, *reinterpret_cast<const u16x8*>(tile + abase + ((32 + lg*8) ^ asw)));
    f32x4 qa[4];
    #pragma unroll
    for (int nt=0; nt<4; ++nt){
      f32x4 z = {0.f,0.f,0.f,0.f};
      z = mfma16(a0, WqF[nt*2+0], z);
      z = mfma16(a1, WqF[nt*2+1], z);
      qa[nt] = z;
    }
    #pragma unroll
    for (int nt=0; nt<4; ++nt)
      #pragma unroll
      for (int r=0; r<4; ++r) qa[nt][r] += bqv[nt];
    float mx[4];
    #pragma unroll
    for (int r=0;r<4;++r) mx[r] = fmaxf(fmaxf(qa[0][r],qa[1][r]), fmaxf(qa[2][r],qa[3][r]));
    #pragma unroll
    for (int off=1; off<16; off<<=1)
      #pragma unroll
      for (int r=0;r<4;++r) mx[r] = fmaxf(mx[r], __shfl_xor(mx[r], off, 64));
    float sm[4] = {0.f,0.f,0.f,0.f};
    #pragma unroll
    for (int nt=0;nt<4;++nt)
      #pragma unroll
      for (int r=0;r<4;++r){ float e = __expf(qa[nt][r]-mx[r]); qa[nt][r]=e; sm[r]+=e; }
    #pragma unroll
    for (int off=1; off<16; off<<=1)
      #pragma unroll
      for (int r=0;r<4;++r) sm[r] += __shfl_xor(sm[r], off, 64);
    float inv[4];
    #pragma unroll
    for (int r=0;r<4;++r) inv[r] = 1.f/sm[r];
    #pragma unroll
    for (int nt=0;nt<4;++nt)
      #pragma unroll
      for (int r=0;r<4;++r){
        int row = mt*16 + lg*4 + r, col = nt*16 + l15;
        tile[row*64 + (col ^ ((row&7)<<3))] = f2bf(qa[nt][r]*inv[r]);
      }
    bf16x8 p0 = __builtin_bit_cast(bf16x8, *reinterpret_cast<const u16x8*>(tile + abase + ((     lg*8) ^ asw)));
    bf16x8 p1 = __builtin_bit_cast(bf16x8, *reinterpret_cast<const u16x8*>(tile + abase + ((32 + lg*8) ^ asw)));
    f32x4 ao[4];
    #pragma unroll
    for (int nt=0; nt<4; ++nt){
      f32x4 z = {0.f,0.f,0.f,0.f};
      z = mfma16(p0, CWF[nt*2+0], z);
      z = mfma16(p1, CWF[nt*2+1], z);
      ao[nt] = z;
    }
    float txv[4][4];
    float s1v[4] = {0.f,0.f,0.f,0.f}, s2v[4] = {0.f,0.f,0.f,0.f};
    #pragma unroll
    for (int nt=0;nt<4;++nt)
      #pragma unroll
      for (int r=0;r<4;++r){
        size_t row = (size_t)(tok0 + mt*16 + lg*4 + r);
        float v = ao[nt][r] + brv[nt] + x[row*64 + nt*16+l15];
        g_txb[row*64 + nt*16+l15] = f2bf(v);
        txv[nt][r] = v; s1v[r] += v; s2v[r] += v*v;
      }
    #pragma unroll
    for (int off=1; off<16; off<<=1)
      #pragma unroll
      for (int r=0;r<4;++r){ s1v[r] += __shfl_xor(s1v[r], off, 64); s2v[r] += __shfl_xor(s2v[r], off, 64); }
    #pragma unroll
    for (int r=0;r<4;++r){
      float mu2 = s1v[r]*(1.f/64.f);
      float rs  = rsqrtf(s2v[r]*(1.f/64.f) - mu2*mu2 + 1e-5f);
      s1v[r] = mu2; s2v[r] = rs;
    }
    #pragma unroll
    for (int nt=0;nt<4;++nt)
      #pragma unroll
      for (int r=0;r<4;++r){
        int row = mt*16 + lg*4 + r, col = nt*16 + l15;
        float n2 = (txv[nt][r]-s1v[r])*s2v[r]*g2v[nt] + be2v[nt];
        tile[row*64 + (col ^ ((row&7)<<3))] = f2bf(n2);
      }
  }

  // ---- copy n2 tile -> global (wide, coalesced; unswizzle on read) ----
  #pragma unroll
  for (int c=0;c<8;++c){
    int idx = c*64 + l;
    int tok = idx>>3, b8 = (idx&7)*8;
    u16x8 v = *reinterpret_cast<const u16x8*>(tile + tok*64 + (b8 ^ ((tok&7)<<3)));
    *reinterpret_cast<u16x8*>(n2g + (size_t)(tok0+tok)*64 + b8) = v;
  }
}

// ============ k3: W1 (on-the-fly) + depthwise conv3x3 + GELU + W2 — rolling row window ============
// Block = 16 x-tok x 16 y-rows, 256 thr (4 waves). Ring rows are COMPUTED:
// h = n2_window(32tok) @ W1^T + b1 via MFMA, masked to exact zeros outside the
// image (SAME padding). Conv/GELU/W2 as r5. One barrier per y-iter.
__global__ __launch_bounds__(256,2) void k3_conv_ffn2(
  const unsigned short* __restrict__ n2g,
  const float* __restrict__ dwp,
  const float* __restrict__ b1,
  const float* __restrict__ b2,
  const unsigned short* __restrict__ wf,
  const unsigned short* __restrict__ g_txb, float* __restrict__ out)
{
  __shared__ unsigned short ring[4][4608];   // 18 tok x 256 ch' (swizzled), 9 KB/slot
  __shared__ unsigned short n2s[2][2048];    // 32 tok x 64 ch (swizzled), 4 KB/buf
  __shared__ unsigned short obuf[2][4096];   // 16 tok x 256 ch' (swizzled), 8 KB/buf
  const int t = threadIdx.x, w = t>>6, l = t&63;
  const int l15 = l&15, lg = l>>4;
  const int bid = (blockIdx.x & 7)*128 + (blockIdx.x >> 3);   // XCD-chunked remap
  const int img = bid>>6;
  const int r6  = bid&63;
  const int y0  = (r6>>3)*16, xb = (r6&7)*16;

  // conv taps + bias for lane channel c' = t (k0 pre-permuted)
  const float4 tA = *reinterpret_cast<const float4*>(&dwp[t*12]);
  const float4 tB = *reinterpret_cast<const float4*>(&dwp[t*12+4]);
  const float4 tC = *reinterpret_cast<const float4*>(&dwp[t*12+8]);  // tap8, conv bias

  // W2 frags for output quarter ntc = w
  bf16x8 W2F[8];
  #pragma unroll
  for (int q=0;q<8;++q)
    W2F[q] = ldfrag_g(wf + 32768 + (w*8 + q)*512 + l*8);
  const float4 b2q = *reinterpret_cast<const float4*>(&b2[w*16 + lg*4]);

  // W1 bias for this wave's nt2 = w*4+q
  float b1w[4];
  #pragma unroll
  for (int q=0;q<4;++q) b1w[q] = b1[(w*4+q)*16 + l15];

  // n2 global staging: thread loads window token si, 8-ch chunk sb
  const int si = t>>3, sb = (t&7)*8;
  const unsigned short* n2img = n2g + (size_t)img*16384*64;

  // load one n2 window row (clamped) into regs
  auto ldstage = [&](int r, u16x8* v){
    int rc = r < 0 ? 0 : (r > 127 ? 127 : r);
    int xx = xb - 8 + si; xx = xx < 0 ? 0 : (xx > 127 ? 127 : xx);
    *v = *reinterpret_cast<const u16x8*>(n2img + ((size_t)rc*128 + xx)*64 + sb);
  };
  auto stwrite = [&](int buf, u16x8 v){
    *reinterpret_cast<u16x8*>(&n2s[buf][si*64 + (sb ^ ((si&7)<<3))]) = v;
  };
  // W1 for row r from staged n2 -> ring slot sl (masked SAME-pad zeros)
  auto W1row = [&](int sl, int r, const unsigned short* ns){
    const bool rv = (r >= 0 && r < 128);
    bf16x8 a00, a01, a10, a11;
    {
      int tok = l15, sw = (tok&7)<<3, ab = tok*64;
      a00 = __builtin_bit_cast(bf16x8, *reinterpret_cast<const u16x8*>(ns + ab + ((     lg*8)^sw)));
      a01 = __builtin_bit_cast(bf16x8, *reinterpret_cast<const u16x8*>(ns + ab + ((32 + lg*8)^sw)));
    }
    {
      int tok = 16 + l15, sw = (tok&7)<<3, ab = tok*64;
      a10 = __builtin_bit_cast(bf16x8, *reinterpret_cast<const u16x8*>(ns + ab + ((     lg*8)^sw)));
      a11 = __builtin_bit_cast(bf16x8, *reinterpret_cast<const u16x8*>(ns + ab + ((32 + lg*8)^sw)));
    }
    unsigned short* rg = ring[sl];
    #pragma unroll
    for (int q=0;q<4;++q){
      const int nt2 = w*4 + q;
      bf16x8 w0 = ldfrag_g(wf + 16384 + (nt2*2+0)*512 + l*8);
      bf16x8 w1 = ldfrag_g(wf + 16384 + (nt2*2+1)*512 + l*8);
      const int cp = l15*16 + nt2;
      #pragma unroll
      for (int mt2=0; mt2<2; ++mt2){
        f32x4 h = {b1w[q], b1w[q], b1w[q], b1w[q]};
        h = mfma16(mt2 ? a10 : a00, w0, h);
        h = mfma16(mt2 ? a11 : a01, w1, h);
        #pragma unroll
        for (int r4=0; r4<4; ++r4){
          int p = mt2*16 + lg*4 + r4 - 7;
          if (p >= 0 && p < 18){
            int xx = xb - 1 + p;
            float v = (rv && xx >= 0 && xx < 128) ? h[r4] : 0.f;
            rg[p*256 + (cp ^ ((p&3)<<4))] = f2bf(v);
          }
        }
      }
    }
  };

  // ---- prologue: h rows y0-1, y0, y0+1 into slots 0,1,2; n2(y0+2) staged ----
  {
    u16x8 sv;
    ldstage(y0-1, &sv); stwrite(0, sv); __syncthreads();
    W1row(0, y0-1, n2s[0]);
    ldstage(y0, &sv); stwrite(1, sv); __syncthreads();
    W1row(1, y0, n2s[1]);
    ldstage(y0+1, &sv); stwrite(0, sv); __syncthreads();
    W1row(2, y0+1, n2s[0]);
    ldstage(y0+2, &sv); stwrite(1, sv); __syncthreads();
  }

  for (int yy=0; yy<16; ++yy){
    const int gy = y0 + yy;
    // (a) issue next n2 row loads (T14 issue-early)
    u16x8 sv;
    if (yy < 15) ldstage(gy+3, &sv);
    // epilogue residual prefetch
    const size_t gtok = (size_t)img*16384 + (size_t)gy*128 + xb + l15;
    const u16x4v tq = *reinterpret_cast<const u16x4v*>(&g_txb[gtok*64 + w*16 + lg*4]);

    // (b) W1: h row gy+2 -> ring slot (yy+3)&3, from n2s[(yy+1)&1]
    W1row((yy+3)&3, gy+2, n2s[(yy+1)&1]);

    // (d) conv row gy from ring slots yy, yy+1, yy+2
    {
      const unsigned short* rA16 = ring[(yy  )&3];
      const unsigned short* rB16 = ring[(yy+1)&3];
      const unsigned short* rC16 = ring[(yy+2)&3];
      unsigned short* ob = obuf[yy&1];
      const int c0 = t, c1 = t^16, c2 = t^32;
      float pA=bf2f(rA16[c0]),      pB=bf2f(rB16[c0]),      pC=bf2f(rC16[c0]);
      float cA=bf2f(rA16[256+c1]),  cB=bf2f(rB16[256+c1]),  cC=bf2f(rC16[256+c1]);
      unsigned short qA=rA16[512+c2], qB=rB16[512+c2], qC=rC16[512+c2];
      #pragma unroll
      for (int s=0;s<16;++s){
        const int oo = (s<15 ? s+3 : 17);
        const int oc = oo*256 + (t ^ ((oo&3)<<4));
        unsigned short zA=rA16[oc], zB=rB16[oc], zC=rC16[oc];
        float nA=bf2f(qA), nB=bf2f(qB), nC=bf2f(qC);
        float a = tC.y;
        a = fmaf(tA.x,pA, a); a = fmaf(tA.y,cA, a); a = fmaf(tA.z,nA, a);
        a = fmaf(tA.w,pB, a); a = fmaf(tB.x,cB, a); a = fmaf(tB.y,nB, a);
        a = fmaf(tB.z,pC, a); a = fmaf(tB.w,cC, a); a = fmaf(tC.x,nC, a);
        float u2 = a*a;
        float arg = a*(-2.3022082f - 0.1029432f*u2);
        float e = __builtin_amdgcn_exp2f(arg);
        float g = a*__builtin_amdgcn_rcpf(1.f + e);
        ob[s*256 + (t ^ ((s&7)<<3))] = f2bf(g);
        pA=cA; pB=cB; pC=cC; cA=nA; cB=nB; cC=nC; qA=zA; qB=zB; qC=zC;
      }
    }
    // stage-write next n2 row (write-late)
    if (yy < 15) stwrite(yy&1, sv);
    __syncthreads();   // (e) — the single per-iter barrier

    // (f) W2: wave w computes output quarter w over K=256 + fused epilogue
    f32x4 oacc = {0.f,0.f,0.f,0.f};
    const int nsw = (l15&7)<<3;
    const unsigned short* ob = obuf[yy&1];
    #pragma unroll
    for (int i=0;i<4;++i){
      bf16x8 fb0 = __builtin_bit_cast(bf16x8,
        *reinterpret_cast<const u16x8*>(&ob[l15*256 + ((i*64      + lg*8) ^ nsw)]));
      bf16x8 fb1 = __builtin_bit_cast(bf16x8,
        *reinterpret_cast<const u16x8*>(&ob[l15*256 + ((i*64 + 32 + lg*8) ^ nsw)]));
      oacc = mfma16(W2F[i*2+0], fb0, oacc);
      oacc = mfma16(W2F[i*2+1], fb1, oacc);
    }
    float4 o;
    o.x = oacc[0] + b2q.x + bf2f(tq[0]);
    o.y = oacc[1] + b2q.y + bf2f(tq[1]);
    o.z = oacc[2] + b2q.z + bf2f(tq[2]);
    o.w = oacc[3] + b2q.w + bf2f(tq[3]);
    *reinterpret_cast<float4*>(&out[gtok*64 + w*16 + lg*4]) = o;
  }
}

extern "C" void kernel_launch(void* const* d_in, const int* in_sizes, int n_in,
                              void* d_out, int out_size, void* d_ws, size_t ws_size,
                              hipStream_t stream)
{
  const float* x  =(const float*)d_in[0];
  const float* g1 =(const float*)d_in[3];
  const float* be1=(const float*)d_in[4];
  const float* Wk =(const float*)d_in[5];
  const float* bk =(const float*)d_in[6];
  const float* Wq =(const float*)d_in[7];
  const float* bq =(const float*)d_in[8];
  const float* Wv =(const float*)d_in[9];
  const float* bv =(const float*)d_in[10];
  const float* Wr =(const float*)d_in[11];
  const float* br =(const float*)d_in[12];
  const float* g2 =(const float*)d_in[13];
  const float* be2=(const float*)d_in[14];
  const float* W1 =(const float*)d_in[15];
  const float* b1 =(const float*)d_in[16];
  const float* dww=(const float*)d_in[17];
  const float* dwb=(const float*)d_in[18];
  const float* W2 =(const float*)d_in[19];
  const float* b2 =(const float*)d_in[20];
  float* outp = (float*)d_out;
  char* ws = (char*)d_ws;

  unsigned short* wfb    = (unsigned short*)ws;                 // 96KB
  unsigned short* ctxWrF = (unsigned short*)(ws + 98304);       // 128KB
  float* g_sump = (float*)(ws + 229376);                        // 128KB
  float* g_part = (float*)(ws + 393216);                        // 8MB
  unsigned short* g_txb = (unsigned short*)(ws + 16777216);     // 32MB bf16
  unsigned short* n2g   = (unsigned short*)(ws + 50331648);     // 33.5MB bf16 LN2 output
  float* dwp            = (float*)(ws + 186712064);             // 12KB repacked taps+bias

  hipLaunchKernelGGL(k0_wfrag, dim3(97), dim3(64), 0, stream, Wk, Wq, Wv, Wr, W1, W2, dww, dwb, dwp, wfb);
  hipLaunchKernelGGL(k1_ctx, dim3(512), dim3(256), 0, stream, x, g1, be1, bk, bv, wfb, g_part, g_sump);
  hipLaunchKernelGGL(k15_ctxwr, dim3(16), dim3(512), 0, stream, g_part, g_sump, Wr, ctxWrF);
  hipLaunchKernelGGL(k2_attn_ffn1, dim3(1024), dim3(256), 0, stream,
                     x, g1, be1, bq, br, g2, be2, wfb, ctxWrF, g_txb, n2g);
  hipLaunchKernelGGL(k3_conv_ffn2, dim3(1024), dim3(256), 0, stream,
                     n2g, dwp, b1, b2, wfb, g_txb, outp);
}